// Round 1
// baseline (311.045 us; speedup 1.0000x reference)
//
#include <hip/hip_runtime.h>
#include <math.h>

#define NBINS 32
#define DCOLS 64

// ws layout (float offsets)
#define WS_A     0            // A[32][64]
#define WS_B     2048         // B[32][64]
#define WS_C     4096         // C[32][64]
#define WS_S     6144         // S[64] = exp(clip(logs))/100
#define WS_T     6208         // T[64] = b*exp(clip(logs))/100 + 0.5
#define WS_SUMLS 6272         // scalar sum(clip(logs))

// ---------------------------------------------------------------------------
// Precompute kernel: one block, 64 threads (one per column d).
// Builds the monomial-expanded spline tables:
//   y    = A[k,d] + B[k,d]*xs + C[k,d]*xs^2      (cover case)
//   dlog = B[k,d] + 2*C[k,d]*xs
// ---------------------------------------------------------------------------
__global__ __launch_bounds__(64) void precompute_kernel(
    const float* __restrict__ p, const float* __restrict__ b,
    const float* __restrict__ logs, float* __restrict__ ws)
{
  const int d = threadIdx.x;  // column 0..63

  // --- mesh in double, matching numpy float64 then cast to f32 ---
  double powr[17];
  {
    double rp = 1.0;
    for (int i = 0; i <= 16; i++) { powr[i] = rp; rp *= 1.2; }
  }
  const double x1L = 50.0 * 0.2 / (powr[16] - 1.0);
  float meshf[NBINS + 1];
  for (int i = 0; i <= NBINS; i++) {
    int idx = i - 16;
    int a = idx >= 0 ? idx : -idx;
    double xr = (1.0 - powr[a]) / (1.0 - 1.2);
    xr = (idx >= 0) ? x1L * xr : -x1L * xr;
    meshf[i] = (float)((xr + 50.0) / 100.0);
  }
  meshf[0] = 0.0f;
  meshf[NBINS] = 1.0f;
  float esf[NBINS];
  for (int i = 0; i < NBINS; i++) esf[i] = meshf[i + 1] - meshf[i];

  // --- actnorm column constants ---
  float ls = logs[d];
  ls = fminf(fmaxf(ls, -5.0f), 5.0f);
  const float s = expf(ls);
  const float bd = b[d];

  // --- pdf normalization (trapezoid) ---
  float ep[NBINS - 1];
  float denom = 0.0f;
  for (int j = 0; j < NBINS - 1; j++) {
    ep[j] = expf(p[j * DCOLS + d]);
    denom += ep[j] * ((esf[j] + esf[j + 1]) * 0.5f);
  }
  const float fnorm = (1.0f - esf[0]) / denom;
  float pdf[NBINS + 1];
  pdf[0] = 1.0f;
  pdf[NBINS] = 1.0f;
  for (int j = 0; j < NBINS - 1; j++) pdf[j + 1] = ep[j] * fnorm;

  // --- expanded quadratic tables; expansion arithmetic in double ---
  float F = 0.0f;
  for (int k = 0; k < NBINS; k++) {
    const double v1 = (double)pdf[k];
    const double v2 = (double)pdf[k + 1];
    const double h  = (double)esf[k];
    const double m  = (double)meshf[k];
    const double c2 = 0.5 * (v2 - v1) / h;
    const double c1 = v1;
    const double A  = (double)F - c1 * m + c2 * m * m;
    const double B  = c1 - 2.0 * c2 * m;
    ws[WS_A + k * DCOLS + d] = (float)A;
    ws[WS_B + k * DCOLS + d] = (float)B;
    ws[WS_C + k * DCOLS + d] = (float)c2;
    const float cell = 0.5f * (pdf[k] + pdf[k + 1]) * esf[k];
    F += cell;
  }

  // --- per-column affine fold: xs = x*S + T ---
  ws[WS_S + d] = (float)((double)s * 0.01);
  ws[WS_T + d] = (float)((double)bd * (double)s * 0.01 + 0.5);

  // --- sum(clip(logs)) over 64 columns ---
  float sum = ls;
  for (int m = 1; m < 64; m <<= 1) sum += __shfl_xor(sum, m, 64);
  if (d == 0) ws[WS_SUMLS] = sum;
}

// ---------------------------------------------------------------------------
// Main kernel: one wave per row (lane = column), 4 rows per wave-iteration.
// ---------------------------------------------------------------------------
__global__ __launch_bounds__(256) void fwd_kernel(
    const float* __restrict__ x, const float* __restrict__ logdet_in,
    const float* __restrict__ ws, float* __restrict__ out,
    float* __restrict__ logdet_out, int nrows, float C1, float INVLNR)
{
  __shared__ float sA[NBINS * DCOLS];
  __shared__ float sB[NBINS * DCOLS];
  __shared__ float sC[NBINS * DCOLS];
  for (int i = threadIdx.x; i < NBINS * DCOLS; i += 256) {
    sA[i] = ws[WS_A + i];
    sB[i] = ws[WS_B + i];
    sC[i] = ws[WS_C + i];
  }
  const int lane = threadIdx.x & 63;
  const int wid  = threadIdx.x >> 6;           // wave in block, 0..3
  const float S     = ws[WS_S + lane];
  const float T     = ws[WS_T + lane];
  const float sumls = ws[WS_SUMLS];
  __syncthreads();

  const int gw = blockIdx.x * 4 + wid;         // global wave id
  const int nw = gridDim.x * 4;                // total waves

  for (int r0 = gw * 4; r0 < nrows; r0 += nw * 4) {
    float res[4], prod[4];
#pragma unroll
    for (int j = 0; j < 4; j++) {
      const int r = r0 + j;
      const float xv = x[(size_t)r * DCOLS + lane];
      const float xs = fmaf(xv, S, T);                       // (z+50)/100
      const float a  = fabsf(xs - 0.5f);
      const float u  = logf(fmaf(a, C1, 1.0f)) * INVLNR;
      const float mfl = floorf(u);
      const float kf  = (xs >= 0.5f) ? (16.0f + mfl) : (15.0f - mfl);
      const int k = (int)kf;
      const bool cover = (k >= 0) && (k <= NBINS - 1);
      int kc = k < 0 ? 0 : (k > NBINS - 1 ? NBINS - 1 : k);
      const int idx = kc * DCOLS + lane;                     // bank = lane%32: conflict-free
      const float Av = sA[idx];
      const float Bv = sB[idx];
      const float Cv = sC[idx];
      const float y  = cover ? fmaf(xs, fmaf(xs, Cv, Bv), Av) : xs;
      const float dl = cover ? fmaf(xs, 2.0f * Cv, Bv) : 1.0f;
      res[j]  = fmaf(y, 100.0f, -50.0f);                     // y*2*BOUND - BOUND
      prod[j] = dl;
    }
#pragma unroll
    for (int j = 0; j < 4; j++)
      out[(size_t)(r0 + j) * DCOLS + lane] = res[j];

    // per-row product of dlog across 64 lanes -> one log per row
#pragma unroll
    for (int j = 0; j < 4; j++) {
      float pr = prod[j];
      for (int m = 1; m < 64; m <<= 1) pr *= __shfl_xor(pr, m, 64);
      prod[j] = pr;
    }
    // lane j (j<4) writes row r0+j; select statically to avoid scratch
    float pr = prod[0];
    pr = (lane == 1) ? prod[1] : pr;
    pr = (lane == 2) ? prod[2] : pr;
    pr = (lane == 3) ? prod[3] : pr;
    if (lane < 4) {
      const int r = r0 + lane;
      logdet_out[r] = logdet_in[r] + sumls + logf(pr);
    }
  }
}

extern "C" void kernel_launch(void* const* d_in, const int* in_sizes, int n_in,
                              void* d_out, int out_size, void* d_ws, size_t ws_size,
                              hipStream_t stream) {
  const float* x      = (const float*)d_in[0];
  const float* logdet = (const float*)d_in[1];
  const float* p      = (const float*)d_in[2];
  const float* b      = (const float*)d_in[3];
  const float* logs   = (const float*)d_in[4];
  float* out = (float*)d_out;
  float* ws  = (float*)d_ws;

  const int N = in_sizes[0] / DCOLS;           // 524288
  float* logdet_out = out + (size_t)N * DCOLS;

  precompute_kernel<<<1, 64, 0, stream>>>(p, b, logs, ws);

  double Rm = 1.0;
  for (int i = 0; i < 16; i++) Rm *= 1.2;
  const double x1L = 50.0 * (1.2 - 1.0) / (Rm - 1.0);
  const double X1L = x1L / 100.0;
  const float C1     = (float)((1.2 - 1.0) / X1L);
  const float INVLNR = (float)(1.0 / log(1.2));

  const int grid = 2048;                       // 16 grid-stride iterations
  fwd_kernel<<<grid, 256, 0, stream>>>(x, logdet, ws, out, logdet_out, N,
                                       C1, INVLNR);
}

// Round 2
// 250.927 us; speedup vs baseline: 1.2396x; 1.2396x over previous
//
#include <hip/hip_runtime.h>
#include <math.h>

#define NBINS 32
#define DCOLS 64

// ws layout (float offsets)
#define WS_A     0            // A[32][64]
#define WS_B     2048         // B[32][64]
#define WS_C     4096         // C[32][64]
#define WS_S     6144         // S[64] = exp(clip(logs))/100
#define WS_T     6208         // T[64] = b*exp(clip(logs))/100 + 0.5
#define WS_SUMLS 6272         // scalar sum(clip(logs))

// ---------------------------------------------------------------------------
// Precompute kernel: one block, 64 threads (one per column d).
//   y    = A[k,d] + B[k,d]*xs + C[k,d]*xs^2      (cover case)
//   dlog = B[k,d] + 2*C[k,d]*xs
// ---------------------------------------------------------------------------
__global__ __launch_bounds__(64) void precompute_kernel(
    const float* __restrict__ p, const float* __restrict__ b,
    const float* __restrict__ logs, float* __restrict__ ws)
{
  const int d = threadIdx.x;  // column 0..63

  double powr[17];
  {
    double rp = 1.0;
    for (int i = 0; i <= 16; i++) { powr[i] = rp; rp *= 1.2; }
  }
  const double x1L = 50.0 * 0.2 / (powr[16] - 1.0);
  float meshf[NBINS + 1];
  for (int i = 0; i <= NBINS; i++) {
    int idx = i - 16;
    int a = idx >= 0 ? idx : -idx;
    double xr = (1.0 - powr[a]) / (1.0 - 1.2);
    xr = (idx >= 0) ? x1L * xr : -x1L * xr;
    meshf[i] = (float)((xr + 50.0) / 100.0);
  }
  meshf[0] = 0.0f;
  meshf[NBINS] = 1.0f;
  float esf[NBINS];
  for (int i = 0; i < NBINS; i++) esf[i] = meshf[i + 1] - meshf[i];

  float ls = logs[d];
  ls = fminf(fmaxf(ls, -5.0f), 5.0f);
  const float s = expf(ls);
  const float bd = b[d];

  float ep[NBINS - 1];
  float denom = 0.0f;
  for (int j = 0; j < NBINS - 1; j++) {
    ep[j] = expf(p[j * DCOLS + d]);
    denom += ep[j] * ((esf[j] + esf[j + 1]) * 0.5f);
  }
  const float fnorm = (1.0f - esf[0]) / denom;
  float pdf[NBINS + 1];
  pdf[0] = 1.0f;
  pdf[NBINS] = 1.0f;
  for (int j = 0; j < NBINS - 1; j++) pdf[j + 1] = ep[j] * fnorm;

  float F = 0.0f;
  for (int k = 0; k < NBINS; k++) {
    const double v1 = (double)pdf[k];
    const double v2 = (double)pdf[k + 1];
    const double h  = (double)esf[k];
    const double m  = (double)meshf[k];
    const double c2 = 0.5 * (v2 - v1) / h;
    const double c1 = v1;
    const double A  = (double)F - c1 * m + c2 * m * m;
    const double B  = c1 - 2.0 * c2 * m;
    ws[WS_A + k * DCOLS + d] = (float)A;
    ws[WS_B + k * DCOLS + d] = (float)B;
    ws[WS_C + k * DCOLS + d] = (float)c2;
    const float cell = 0.5f * (pdf[k] + pdf[k + 1]) * esf[k];
    F += cell;
  }

  ws[WS_S + d] = (float)((double)s * 0.01);
  ws[WS_T + d] = (float)((double)bd * (double)s * 0.01 + 0.5);

  float sum = ls;
  for (int m = 1; m < 64; m <<= 1) sum += __shfl_xor(sum, m, 64);
  if (d == 0) ws[WS_SUMLS] = sum;
}

// ---------------------------------------------------------------------------
// Per-float4 spline evaluation (4 consecutive columns c0..c0+3).
// ---------------------------------------------------------------------------
__device__ __forceinline__ void proc4(
    const float4 xv, const float4 S4, const float4 T4,
    const float* __restrict__ sA, const float* __restrict__ sB,
    const float* __restrict__ sC, int c0, float C1, float INVL2R,
    float4& res, float& prod)
{
  float xs_[4] = { fmaf(xv.x, S4.x, T4.x), fmaf(xv.y, S4.y, T4.y),
                   fmaf(xv.z, S4.z, T4.z), fmaf(xv.w, S4.w, T4.w) };
  float r_[4];
  float pr = 1.0f;
#pragma unroll
  for (int i = 0; i < 4; i++) {
    const float xs = xs_[i];
    const float a  = fabsf(xs - 0.5f);
    const float u  = __log2f(fmaf(a, C1, 1.0f)) * INVL2R;
    const float mfl = floorf(u);
    const float kf  = (xs >= 0.5f) ? (16.0f + mfl) : (15.0f - mfl);
    const int k = (int)kf;
    const bool cover = (k >= 0) && (k <= NBINS - 1);
    const int kc = k < 0 ? 0 : (k > NBINS - 1 ? NBINS - 1 : k);
    const int idx = kc * DCOLS + c0 + i;
    const float Av = sA[idx];
    const float Bv = sB[idx];
    const float Cv = sC[idx];
    const float y  = cover ? fmaf(xs, fmaf(xs, Cv, Bv), Av) : xs;
    const float dl = cover ? fmaf(xs, 2.0f * Cv, Bv) : 1.0f;
    r_[i] = fmaf(y, 100.0f, -50.0f);
    pr *= dl;
  }
  res = make_float4(r_[0], r_[1], r_[2], r_[3]);
  prod = pr;
}

// ---------------------------------------------------------------------------
// Main kernel: lane = (row-sub 0..3, col-group 0..15); float4 per lane.
// Each wave: 8 rows per iteration (2 groups of 4, 2 dwordx4 loads in flight).
// ---------------------------------------------------------------------------
__global__ __launch_bounds__(256) void fwd_kernel(
    const float* __restrict__ x, const float* __restrict__ logdet_in,
    const float* __restrict__ ws, float* __restrict__ out,
    float* __restrict__ logdet_out, int nrows, float C1, float INVL2R)
{
  __shared__ float sA[NBINS * DCOLS];
  __shared__ float sB[NBINS * DCOLS];
  __shared__ float sC[NBINS * DCOLS];
  // vectorized staging: 1536 float4 across 256 threads
  {
    const float4* wsv = (const float4*)(ws);
    float4* sAv = (float4*)sA;
    float4* sBv = (float4*)sB;
    float4* sCv = (float4*)sC;
    for (int i = threadIdx.x; i < (NBINS * DCOLS) / 4; i += 256) {
      sAv[i] = wsv[(WS_A / 4) + i];
      sBv[i] = wsv[(WS_B / 4) + i];
      sCv[i] = wsv[(WS_C / 4) + i];
    }
  }
  const int lane = threadIdx.x & 63;
  const int wid  = threadIdx.x >> 6;   // wave in block 0..3
  const int cg   = lane & 15;          // column group 0..15
  const int rs   = lane >> 4;          // row sub 0..3
  const int c0   = cg * 4;
  const float4 S4 = *(const float4*)(ws + WS_S + c0);
  const float4 T4 = *(const float4*)(ws + WS_T + c0);
  const float sumls = ws[WS_SUMLS];
  __syncthreads();

  const int gw = blockIdx.x * 4 + wid;
  const int nw = gridDim.x * 4;

  for (int r0 = gw * 8; r0 < nrows; r0 += nw * 8) {
    const int rA = r0 + rs;
    const int rB = r0 + 4 + rs;
    const float4 xA = *(const float4*)(x + (size_t)rA * DCOLS + c0);
    const float4 xB = *(const float4*)(x + (size_t)rB * DCOLS + c0);

    float4 resA, resB;
    float pA, pB;
    proc4(xA, S4, T4, sA, sB, sC, c0, C1, INVL2R, resA, pA);
    proc4(xB, S4, T4, sA, sB, sC, c0, C1, INVL2R, resB, pB);

    *(float4*)(out + (size_t)rA * DCOLS + c0) = resA;
    *(float4*)(out + (size_t)rB * DCOLS + c0) = resB;

    // product over the 16 lanes of each row group
#pragma unroll
    for (int m = 1; m < 16; m <<= 1) {
      pA *= __shfl_xor(pA, m, 64);
      pB *= __shfl_xor(pB, m, 64);
    }
    if (cg == 0) {
      logdet_out[rA] = logdet_in[rA] + sumls + logf(pA);
      logdet_out[rB] = logdet_in[rB] + sumls + logf(pB);
    }
  }
}

extern "C" void kernel_launch(void* const* d_in, const int* in_sizes, int n_in,
                              void* d_out, int out_size, void* d_ws, size_t ws_size,
                              hipStream_t stream) {
  const float* x      = (const float*)d_in[0];
  const float* logdet = (const float*)d_in[1];
  const float* p      = (const float*)d_in[2];
  const float* b      = (const float*)d_in[3];
  const float* logs   = (const float*)d_in[4];
  float* out = (float*)d_out;
  float* ws  = (float*)d_ws;

  const int N = in_sizes[0] / DCOLS;           // 524288
  float* logdet_out = out + (size_t)N * DCOLS;

  precompute_kernel<<<1, 64, 0, stream>>>(p, b, logs, ws);

  double Rm = 1.0;
  for (int i = 0; i < 16; i++) Rm *= 1.2;
  const double x1L = 50.0 * (1.2 - 1.0) / (Rm - 1.0);
  const double X1L = x1L / 100.0;
  const float C1      = (float)((1.2 - 1.0) / X1L);
  const float INVL2R  = (float)(1.0 / log2(1.2));

  const int grid = 2048;
  fwd_kernel<<<grid, 256, 0, stream>>>(x, logdet, ws, out, logdet_out, N,
                                       C1, INVL2R);
}

// Round 3
// 248.891 us; speedup vs baseline: 1.2497x; 1.0082x over previous
//
#include <hip/hip_runtime.h>
#include <math.h>

#define NBINS 32
#define DCOLS 64

// ws layout (float offsets)
#define WS_A     0            // A[32][64]  (column-swizzled)
#define WS_B     2048         // B[32][64]  (column-swizzled)
#define WS_C     4096         // C[32][64]  (column-swizzled)
#define WS_S     6144         // S[64] = exp(clip(logs))/100
#define WS_T     6208         // T[64] = b*exp(clip(logs))/100 + 0.5
#define WS_SUMLS 6272         // scalar sum(clip(logs))

// Column swizzle: d = 4*cg + i  ->  16*i + cg.  For a fixed i, the 16
// column-groups land in 16 DISTINCT banks (16i+cg mod 32) => worst-case
// 4-way (row-subs), often broadcast when k coincides.
__device__ __forceinline__ int swz(int d) { return ((d & 3) << 4) | (d >> 2); }

// ---------------------------------------------------------------------------
// Precompute kernel: one block, 64 threads (one per column d).
//   y    = A[k,d] + B[k,d]*xs + C[k,d]*xs^2      (cover case)
//   dlog = B[k,d] + 2*C[k,d]*xs
// ---------------------------------------------------------------------------
__global__ __launch_bounds__(64) void precompute_kernel(
    const float* __restrict__ p, const float* __restrict__ b,
    const float* __restrict__ logs, float* __restrict__ ws)
{
  const int d = threadIdx.x;  // column 0..63
  const int ds = swz(d);      // swizzled column slot

  double powr[17];
  {
    double rp = 1.0;
    for (int i = 0; i <= 16; i++) { powr[i] = rp; rp *= 1.2; }
  }
  const double x1L = 50.0 * 0.2 / (powr[16] - 1.0);
  float meshf[NBINS + 1];
  for (int i = 0; i <= NBINS; i++) {
    int idx = i - 16;
    int a = idx >= 0 ? idx : -idx;
    double xr = (1.0 - powr[a]) / (1.0 - 1.2);
    xr = (idx >= 0) ? x1L * xr : -x1L * xr;
    meshf[i] = (float)((xr + 50.0) / 100.0);
  }
  meshf[0] = 0.0f;
  meshf[NBINS] = 1.0f;
  float esf[NBINS];
  for (int i = 0; i < NBINS; i++) esf[i] = meshf[i + 1] - meshf[i];

  float ls = logs[d];
  ls = fminf(fmaxf(ls, -5.0f), 5.0f);
  const float s = expf(ls);
  const float bd = b[d];

  float ep[NBINS - 1];
  float denom = 0.0f;
  for (int j = 0; j < NBINS - 1; j++) {
    ep[j] = expf(p[j * DCOLS + d]);
    denom += ep[j] * ((esf[j] + esf[j + 1]) * 0.5f);
  }
  const float fnorm = (1.0f - esf[0]) / denom;
  float pdf[NBINS + 1];
  pdf[0] = 1.0f;
  pdf[NBINS] = 1.0f;
  for (int j = 0; j < NBINS - 1; j++) pdf[j + 1] = ep[j] * fnorm;

  float F = 0.0f;
  for (int k = 0; k < NBINS; k++) {
    const double v1 = (double)pdf[k];
    const double v2 = (double)pdf[k + 1];
    const double h  = (double)esf[k];
    const double m  = (double)meshf[k];
    const double c2 = 0.5 * (v2 - v1) / h;
    const double c1 = v1;
    const double A  = (double)F - c1 * m + c2 * m * m;
    const double B  = c1 - 2.0 * c2 * m;
    ws[WS_A + k * DCOLS + ds] = (float)A;
    ws[WS_B + k * DCOLS + ds] = (float)B;
    ws[WS_C + k * DCOLS + ds] = (float)c2;
    const float cell = 0.5f * (pdf[k] + pdf[k + 1]) * esf[k];
    F += cell;
  }

  ws[WS_S + d] = (float)((double)s * 0.01);
  ws[WS_T + d] = (float)((double)bd * (double)s * 0.01 + 0.5);

  float sum = ls;
  for (int m = 1; m < 64; m <<= 1) sum += __shfl_xor(sum, m, 64);
  if (d == 0) ws[WS_SUMLS] = sum;
}

// ---------------------------------------------------------------------------
// Per-float4 spline evaluation; cg = column group (0..15); element i lives at
// swizzled LDS slot k*64 + 16*i + cg.
// ---------------------------------------------------------------------------
__device__ __forceinline__ void proc4(
    const float4 xv, const float4 S4, const float4 T4,
    const float* __restrict__ sA, const float* __restrict__ sB,
    const float* __restrict__ sC, int cg, float C1, float INVL2R,
    float4& res, float& prod)
{
  float xs_[4] = { fmaf(xv.x, S4.x, T4.x), fmaf(xv.y, S4.y, T4.y),
                   fmaf(xv.z, S4.z, T4.z), fmaf(xv.w, S4.w, T4.w) };
  float r_[4];
  float pr = 1.0f;
#pragma unroll
  for (int i = 0; i < 4; i++) {
    const float xs = xs_[i];
    const float a  = fabsf(xs - 0.5f);
    const float u  = __log2f(fmaf(a, C1, 1.0f)) * INVL2R;
    const float mfl = floorf(u);
    const float kf  = (xs >= 0.5f) ? (16.0f + mfl) : (15.0f - mfl);
    const int k = (int)kf;
    const bool cover = (k >= 0) && (k <= NBINS - 1);
    const int kc = k < 0 ? 0 : (k > NBINS - 1 ? NBINS - 1 : k);
    const int idx = kc * DCOLS + 16 * i + cg;   // swizzled: 16 distinct banks
    const float Av = sA[idx];
    const float Bv = sB[idx];
    const float Cv = sC[idx];
    const float y  = cover ? fmaf(xs, fmaf(xs, Cv, Bv), Av) : xs;
    const float dl = cover ? fmaf(xs, 2.0f * Cv, Bv) : 1.0f;
    r_[i] = fmaf(y, 100.0f, -50.0f);
    pr *= dl;
  }
  res = make_float4(r_[0], r_[1], r_[2], r_[3]);
  prod = pr;
}

// ---------------------------------------------------------------------------
// Main kernel: lane = (row-sub 0..3, col-group 0..15); float4 per lane.
// 16 rows per wave-iteration (4 dwordx4 loads in flight per lane).
// ---------------------------------------------------------------------------
__global__ __launch_bounds__(256) void fwd_kernel(
    const float* __restrict__ x, const float* __restrict__ logdet_in,
    const float* __restrict__ ws, float* __restrict__ out,
    float* __restrict__ logdet_out, int nrows, float C1, float INVL2R)
{
  __shared__ float sA[NBINS * DCOLS];
  __shared__ float sB[NBINS * DCOLS];
  __shared__ float sC[NBINS * DCOLS];
  {
    const float4* wsv = (const float4*)(ws);
    float4* sAv = (float4*)sA;
    float4* sBv = (float4*)sB;
    float4* sCv = (float4*)sC;
    for (int i = threadIdx.x; i < (NBINS * DCOLS) / 4; i += 256) {
      sAv[i] = wsv[(WS_A / 4) + i];
      sBv[i] = wsv[(WS_B / 4) + i];
      sCv[i] = wsv[(WS_C / 4) + i];
    }
  }
  const int lane = threadIdx.x & 63;
  const int wid  = threadIdx.x >> 6;   // wave in block 0..3
  const int cg   = lane & 15;          // column group 0..15
  const int rs   = lane >> 4;          // row sub 0..3
  const int c0   = cg * 4;
  const float4 S4 = *(const float4*)(ws + WS_S + c0);
  const float4 T4 = *(const float4*)(ws + WS_T + c0);
  const float sumls = ws[WS_SUMLS];
  __syncthreads();

  const int gw = blockIdx.x * 4 + wid;
  const int nw = gridDim.x * 4;

  for (int r0 = gw * 16; r0 < nrows; r0 += nw * 16) {
    const int rA = r0 + rs;
    const int rB = r0 + 4 + rs;
    const int rC = r0 + 8 + rs;
    const int rD = r0 + 12 + rs;
    // 4 loads issued back-to-back: 64B in flight per lane
    const float4 xA = *(const float4*)(x + (size_t)rA * DCOLS + c0);
    const float4 xB = *(const float4*)(x + (size_t)rB * DCOLS + c0);
    const float4 xC = *(const float4*)(x + (size_t)rC * DCOLS + c0);
    const float4 xD = *(const float4*)(x + (size_t)rD * DCOLS + c0);

    float4 resA, resB, resC, resD;
    float pA, pB, pC, pD;
    proc4(xA, S4, T4, sA, sB, sC, cg, C1, INVL2R, resA, pA);
    proc4(xB, S4, T4, sA, sB, sC, cg, C1, INVL2R, resB, pB);
    proc4(xC, S4, T4, sA, sB, sC, cg, C1, INVL2R, resC, pC);
    proc4(xD, S4, T4, sA, sB, sC, cg, C1, INVL2R, resD, pD);

    *(float4*)(out + (size_t)rA * DCOLS + c0) = resA;
    *(float4*)(out + (size_t)rB * DCOLS + c0) = resB;
    *(float4*)(out + (size_t)rC * DCOLS + c0) = resC;
    *(float4*)(out + (size_t)rD * DCOLS + c0) = resD;

    // product over the 16 lanes of each row group
#pragma unroll
    for (int m = 1; m < 16; m <<= 1) {
      pA *= __shfl_xor(pA, m, 64);
      pB *= __shfl_xor(pB, m, 64);
      pC *= __shfl_xor(pC, m, 64);
      pD *= __shfl_xor(pD, m, 64);
    }
    if (cg == 0) {
      logdet_out[rA] = logdet_in[rA] + sumls + logf(pA);
      logdet_out[rB] = logdet_in[rB] + sumls + logf(pB);
      logdet_out[rC] = logdet_in[rC] + sumls + logf(pC);
      logdet_out[rD] = logdet_in[rD] + sumls + logf(pD);
    }
  }
}

extern "C" void kernel_launch(void* const* d_in, const int* in_sizes, int n_in,
                              void* d_out, int out_size, void* d_ws, size_t ws_size,
                              hipStream_t stream) {
  const float* x      = (const float*)d_in[0];
  const float* logdet = (const float*)d_in[1];
  const float* p      = (const float*)d_in[2];
  const float* b      = (const float*)d_in[3];
  const float* logs   = (const float*)d_in[4];
  float* out = (float*)d_out;
  float* ws  = (float*)d_ws;

  const int N = in_sizes[0] / DCOLS;           // 524288
  float* logdet_out = out + (size_t)N * DCOLS;

  precompute_kernel<<<1, 64, 0, stream>>>(p, b, logs, ws);

  double Rm = 1.0;
  for (int i = 0; i < 16; i++) Rm *= 1.2;
  const double x1L = 50.0 * (1.2 - 1.0) / (Rm - 1.0);
  const double X1L = x1L / 100.0;
  const float C1      = (float)((1.2 - 1.0) / X1L);
  const float INVL2R  = (float)(1.0 / log2(1.2));

  const int grid = 2048;
  fwd_kernel<<<grid, 256, 0, stream>>>(x, logdet, ws, out, logdet_out, N,
                                       C1, INVL2R);
}